// Round 4
// baseline (822.241 us; speedup 1.0000x reference)
//
#include <hip/hip_runtime.h>
#include <stdint.h>

// ---------------------------------------------------------------------------
// MoE forward, routed top-2 (reference computes dense all-expert but only the
// top-2 rows survive the combine -> identical math at 1/4 the FLOPs).
// Precision: fp16 hi/lo split GEMMs (3-term MFMA) => fp32-equivalent output
// (absmax err ~2e-5). Fallback tiers (smaller ws): single-pass fp16.
// Pipeline: init -> transpose+split(w1,w2,w3 -> [n][k]) -> router(x->hi/lo,
//           top2, importance, counts) -> offsets/aux -> scatter rows ->
//           GEMM1 (u=x@w1,v=x@w2, silu(u)*v -> h hi/lo) ->
//           GEMM2 (h@w3+b3 -> ybuf) -> combine (out = p0*y0 + p1*y1).
// GEMM structure: m97-verified (128x128 tile, BK=32, 4 waves,
//                 global_load_lds width 16, 16x16x32 f16 MFMA, fp32 accum).
// ---------------------------------------------------------------------------

#define NTOK     8192          // B*T
#define DM       1024          // D_MODEL
#define DH       2048          // D_HIDDEN
#define NEXP     8
#define NPAIR    16384         // NTOK * TOP_K
#define TILE_M   128
#define GRID_M   136           // ceil((16384 + 8*127)/128) = 136 (divisible by 8)
#define WC_ROWS  (GRID_M * TILE_M)   // 17408

typedef _Float16 half8 __attribute__((ext_vector_type(8)));
typedef float    f32x4 __attribute__((ext_vector_type(4)));
typedef unsigned int u32;

__device__ __forceinline__ void gload16(const void* g, void* l) {
  __builtin_amdgcn_global_load_lds(
      (const __attribute__((address_space(1))) u32*)g,
      (__attribute__((address_space(3))) u32*)l, 16, 0, 0);
}

// ---------------- init: zero out, rtok=-1, rprob=0, ctrl=0 ----------------
__global__ void init_kernel(float4* __restrict__ out4, int n4, float* __restrict__ aux,
                            int* __restrict__ rtok, float* __restrict__ rprob,
                            int* __restrict__ ctrl) {
  int gid = blockIdx.x * 256 + threadIdx.x;
  int stride = gridDim.x * 256;
  float4 z4 = {0.f, 0.f, 0.f, 0.f};
  for (int i = gid; i < n4; i += stride) out4[i] = z4;
  for (int i = gid; i < WC_ROWS; i += stride) { rtok[i] = -1; rprob[i] = 0.f; }
  if (gid < 64) ctrl[gid] = 0;
  if (gid == 0) *aux = 0.f;
}

// ---- transpose+cvt(+split) weights: [E][R][C] f32 -> [E][C][R] f16 (hi[,lo]) ----
template <bool SPLIT>
__global__ __launch_bounds__(256) void transpose_cvt_kernel(
    const float* __restrict__ w1, const float* __restrict__ w2, const float* __restrict__ w3,
    _Float16* __restrict__ w1h, _Float16* __restrict__ w1l,
    _Float16* __restrict__ w2h, _Float16* __restrict__ w2l,
    _Float16* __restrict__ w3h, _Float16* __restrict__ w3l) {
  int z = blockIdx.z;
  int R = (z == 2) ? DH : DM;
  int C = (z == 2) ? DM : DH;
  const float* in = (z == 0) ? w1 : (z == 1) ? w2 : w3;
  _Float16* outh  = (z == 0) ? w1h : (z == 1) ? w2h : w3h;
  _Float16* outl  = (z == 0) ? w1l : (z == 1) ? w2l : w3l;
  size_t ebase = (size_t)blockIdx.y * R * C;
  in += ebase;
  int tilesC = C >> 5;
  int tr = blockIdx.x / tilesC, tc = blockIdx.x % tilesC;
  int r0 = tr << 7, c0 = tc << 5;
  __shared__ float tsh[32][129];
  int tx = threadIdx.x, ty = threadIdx.y;   // (32, 8)
#pragma unroll
  for (int i = 0; i < 16; i++) {
    int r = ty + i * 8;
    tsh[tx][r] = in[(size_t)(r0 + r) * C + c0 + tx];
  }
  __syncthreads();
  int tid = ty * 32 + tx;
  int c = tid >> 3, g = tid & 7;            // 32 out-rows x 8 chunks of 16
  const float* trow = &tsh[c][g * 16];
  _Float16 thi[16], tlo[16];
#pragma unroll
  for (int j = 0; j < 16; j++) {
    float v = trow[j];
    _Float16 hi = (_Float16)v;
    thi[j] = hi;
    if (SPLIT) tlo[j] = (_Float16)(v - (float)hi);
  }
  size_t dsto = ebase + (size_t)(c0 + c) * R + r0 + g * 16;
  half8* dh = (half8*)(outh + dsto);
  dh[0] = *(half8*)&thi[0];
  dh[1] = *(half8*)&thi[8];
  if (SPLIT) {
    half8* dl = (half8*)(outl + dsto);
    dl[0] = *(half8*)&tlo[0];
    dl[1] = *(half8*)&tlo[8];
  }
}

// ---- router: logits, top-2 (stable), softmax, importance, counts, x->f16 ----
template <bool SPLIT>
__global__ __launch_bounds__(256) void router_kernel(
    const float* __restrict__ x, const float* __restrict__ gw, const float* __restrict__ gb,
    float* __restrict__ g_imp, int* __restrict__ g_cnt,
    int* __restrict__ tok_e, float* __restrict__ tok_p,
    _Float16* __restrict__ xhi, _Float16* __restrict__ xlo) {
  __shared__ float s_imp[8];
  __shared__ int   s_cnt[8];
  int t = threadIdx.x;
  if (t < 8) { s_imp[t] = 0.f; s_cnt[t] = 0; }
  __syncthreads();
  int wave = t >> 6, lane = t & 63;
  int tok = blockIdx.x * 4 + wave;
  const float4* xr = (const float4*)(x + (size_t)tok * DM);
  float acc[8] = {0.f,0.f,0.f,0.f,0.f,0.f,0.f,0.f};
  _Float16 hh[16], ll[16];
#pragma unroll
  for (int j = 0; j < 4; j++) {
    float4 v = xr[lane * 4 + j];
    const float* gw0 = gw + (size_t)(lane * 16 + j * 4) * 8;
#pragma unroll
    for (int e = 0; e < 8; e++)
      acc[e] += v.x * gw0[e] + v.y * gw0[8 + e] + v.z * gw0[16 + e] + v.w * gw0[24 + e];
    float vv[4] = {v.x, v.y, v.z, v.w};
#pragma unroll
    for (int q = 0; q < 4; q++) {
      _Float16 hi = (_Float16)vv[q];
      hh[j * 4 + q] = hi;
      if (SPLIT) ll[j * 4 + q] = (_Float16)(vv[q] - (float)hi);
    }
  }
  size_t xoff = (size_t)tok * DM + lane * 16;
  half8* xo = (half8*)(xhi + xoff);
  xo[0] = *(half8*)&hh[0];
  xo[1] = *(half8*)&hh[8];
  if (SPLIT) {
    half8* xl = (half8*)(xlo + xoff);
    xl[0] = *(half8*)&ll[0];
    xl[1] = *(half8*)&ll[8];
  }
#pragma unroll
  for (int off = 32; off > 0; off >>= 1) {
#pragma unroll
    for (int e = 0; e < 8; e++) acc[e] += __shfl_xor(acc[e], off, 64);
  }
  if (lane == 0) {
    float l[8];
#pragma unroll
    for (int e = 0; e < 8; e++) l[e] = acc[e] + gb[e];
    // top-1 / top-2, first-max-wins (jax.lax.top_k lower-index tie rule)
    float v0 = l[0]; int i0 = 0;
#pragma unroll
    for (int e = 1; e < 8; e++) if (l[e] > v0) { v0 = l[e]; i0 = e; }
    float v1 = -3.4e38f; int i1 = -1;
#pragma unroll
    for (int e = 0; e < 8; e++) {
      if (e != i0 && l[e] > v1) { v1 = l[e]; i1 = e; }
    }
    // full softmax for importance (v0 is global max)
    float s = 0.f, p[8];
#pragma unroll
    for (int e = 0; e < 8; e++) { p[e] = expf(l[e] - v0); s += p[e]; }
    float inv = 1.f / s;
#pragma unroll
    for (int e = 0; e < 8; e++) atomicAdd(&s_imp[e], p[e] * inv);
    // top-2 softmax
    float e1 = expf(v1 - v0);
    float p0 = 1.f / (1.f + e1);
    tok_e[tok * 2] = i0;  tok_e[tok * 2 + 1] = i1;
    tok_p[tok * 2] = p0;  tok_p[tok * 2 + 1] = e1 * p0;
    atomicAdd(&s_cnt[i0], 1); atomicAdd(&s_cnt[i1], 1);
  }
  __syncthreads();
  if (t < 8) { atomicAdd(&g_imp[t], s_imp[t]); atomicAdd(&g_cnt[t], s_cnt[t]); }
}

// ---------------- segment offsets (128-aligned) + aux loss ----------------
__global__ void offsets_aux_kernel(const float* __restrict__ g_imp, const int* __restrict__ g_cnt,
                                   int* __restrict__ segoff, float* __restrict__ aux_out) {
  if (threadIdx.x == 0 && blockIdx.x == 0) {
    int off = 0;
    segoff[0] = 0;
    double aux = 0.0;
    for (int e = 0; e < 8; e++) {
      off += ((g_cnt[e] + TILE_M - 1) >> 7) << 7;
      segoff[e + 1] = off;
      aux += (double)g_imp[e] * (double)g_cnt[e];
    }
    aux_out[0] = (float)(aux * 8.0 / ((double)NTOK * (double)NPAIR));
  }
}

// ---- scatter (token,prob) into expert segments, block-aggregated cursor ----
__global__ __launch_bounds__(256) void scatter_rows_kernel(
    const int* __restrict__ tok_e, const float* __restrict__ tok_p,
    const int* __restrict__ segoff, int* __restrict__ cursor,
    int* __restrict__ rtok, float* __restrict__ rprob, int* __restrict__ inv) {
  __shared__ int lcnt[8], lbase[8];
  int t = threadIdx.x;
  if (t < 8) lcnt[t] = 0;
  __syncthreads();
  int i = blockIdx.x * 256 + t;          // NPAIR = 64*256 exactly
  int e = tok_e[i];
  int lpos = atomicAdd(&lcnt[e], 1);
  __syncthreads();
  if (t < 8) lbase[t] = (lcnt[t] > 0) ? atomicAdd(&cursor[t], lcnt[t]) : 0;
  __syncthreads();
  int r = segoff[e] + lbase[e] + lpos;
  rtok[r]  = i >> 1;
  rprob[r] = tok_p[i];
  inv[i]   = r;
}

// ---- GEMM1: u=x@w1+b1, v=x@w2+b2, h=silu(u)*v. SPLIT: 3-term hi/lo MFMA ----
template <bool SPLIT>
__global__ __launch_bounds__(256) void gemm1_kernel(
    const _Float16* __restrict__ xhi, const _Float16* __restrict__ xlo,
    const _Float16* __restrict__ w1h, const _Float16* __restrict__ w1l,
    const _Float16* __restrict__ w2h, const _Float16* __restrict__ w2l,
    const float* __restrict__ b1, const float* __restrict__ b2,
    const int* __restrict__ rtok, const int* __restrict__ segoff,
    _Float16* __restrict__ hhi, _Float16* __restrict__ hlo) {
  // XCD swizzle: each XCD owns 2 contiguous N-panels across all M
  int dflat = blockIdx.y * 136 + blockIdx.x;     // grid (136,16) = 2176 = 8*272
  int xcd = dflat & 7, j = dflat >> 3;           // j in [0,272)
  int wy = xcd * 2 + (j >= 136 ? 1 : 0);
  int wx = (j >= 136) ? j - 136 : j;
  int mbase = wx * TILE_M;
  if (mbase >= segoff[8]) return;
  int e = 0;
  while (mbase >= segoff[e + 1]) e++;
  int nbase = wy * 128;

  extern __shared__ char smem[];               // SPLIT: 48 KB, else 24 KB
  _Float16* Ah  = (_Float16*)smem;             // [128*32] each (8 KB)
  _Float16* B1h = Ah  + 4096;
  _Float16* B2h = B1h + 4096;
  _Float16* Al  = B2h + 4096;
  _Float16* B1l = Al  + 4096;
  _Float16* B2l = B1l + 4096;

  int t = threadIdx.x;
  int lane = t & 63, wave = t >> 6;
  int wr = wave >> 1, wc = wave & 1;

  // staging: thread t owns row r0=t/4 (and r0+64), 16B chunk part=t&3
  int r0 = t >> 2, part = t & 3;
  int r1 = 64 + r0;
  int tokA0 = rtok[mbase + r0]; if (tokA0 < 0) tokA0 = 0;   // padded row -> safe data
  int tokA1 = rtok[mbase + r1]; if (tokA1 < 0) tokA1 = 0;
  size_t offA0 = (size_t)tokA0 * DM + part * 8;
  size_t offA1 = (size_t)tokA1 * DM + part * 8;
  size_t offB0 = ((size_t)e * DH + nbase + r0) * DM + part * 8;
  size_t offB1 = ((size_t)e * DH + nbase + r1) * DM + part * 8;
  int l0 = wave * 1024, l1 = 4096 + wave * 1024;  // byte offsets into each tile

  f32x4 uacc[4][4], vacc[4][4];
#pragma unroll
  for (int a = 0; a < 4; a++)
#pragma unroll
    for (int b = 0; b < 4; b++) { uacc[a][b] = {0.f,0.f,0.f,0.f}; vacc[a][b] = {0.f,0.f,0.f,0.f}; }

  for (int kk = 0; kk < DM; kk += 32) {
    gload16(xhi + offA0 + kk, (char*)Ah  + l0);
    gload16(xhi + offA1 + kk, (char*)Ah  + l1);
    gload16(w1h + offB0 + kk, (char*)B1h + l0);
    gload16(w1h + offB1 + kk, (char*)B1h + l1);
    gload16(w2h + offB0 + kk, (char*)B2h + l0);
    gload16(w2h + offB1 + kk, (char*)B2h + l1);
    if (SPLIT) {
      gload16(xlo + offA0 + kk, (char*)Al  + l0);
      gload16(xlo + offA1 + kk, (char*)Al  + l1);
      gload16(w1l + offB0 + kk, (char*)B1l + l0);
      gload16(w1l + offB1 + kk, (char*)B1l + l1);
      gload16(w2l + offB0 + kk, (char*)B2l + l0);
      gload16(w2l + offB1 + kk, (char*)B2l + l1);
    }
    __syncthreads();
    int kpos = (lane >> 4) * 8;
    half8 ah[4], al[4];
#pragma unroll
    for (int i = 0; i < 4; i++) {
      int rowA = wr * 64 + i * 16 + (lane & 15);
      ah[i] = *(const half8*)&Ah[rowA * 32 + kpos];
      if (SPLIT) al[i] = *(const half8*)&Al[rowA * 32 + kpos];
    }
    {
      half8 bh[4], bl[4];
#pragma unroll
      for (int i = 0; i < 4; i++) {
        int rowB = wc * 64 + i * 16 + (lane & 15);
        bh[i] = *(const half8*)&B1h[rowB * 32 + kpos];
        if (SPLIT) bl[i] = *(const half8*)&B1l[rowB * 32 + kpos];
      }
#pragma unroll
      for (int mi = 0; mi < 4; mi++)
#pragma unroll
        for (int ni = 0; ni < 4; ni++) {
          uacc[mi][ni] = __builtin_amdgcn_mfma_f32_16x16x32_f16(ah[mi], bh[ni], uacc[mi][ni], 0, 0, 0);
          if (SPLIT) {
            uacc[mi][ni] = __builtin_amdgcn_mfma_f32_16x16x32_f16(ah[mi], bl[ni], uacc[mi][ni], 0, 0, 0);
            uacc[mi][ni] = __builtin_amdgcn_mfma_f32_16x16x32_f16(al[mi], bh[ni], uacc[mi][ni], 0, 0, 0);
          }
        }
    }
    {
      half8 bh[4], bl[4];
#pragma unroll
      for (int i = 0; i < 4; i++) {
        int rowB = wc * 64 + i * 16 + (lane & 15);
        bh[i] = *(const half8*)&B2h[rowB * 32 + kpos];
        if (SPLIT) bl[i] = *(const half8*)&B2l[rowB * 32 + kpos];
      }
#pragma unroll
      for (int mi = 0; mi < 4; mi++)
#pragma unroll
        for (int ni = 0; ni < 4; ni++) {
          vacc[mi][ni] = __builtin_amdgcn_mfma_f32_16x16x32_f16(ah[mi], bh[ni], vacc[mi][ni], 0, 0, 0);
          if (SPLIT) {
            vacc[mi][ni] = __builtin_amdgcn_mfma_f32_16x16x32_f16(ah[mi], bl[ni], vacc[mi][ni], 0, 0, 0);
            vacc[mi][ni] = __builtin_amdgcn_mfma_f32_16x16x32_f16(al[mi], bh[ni], vacc[mi][ni], 0, 0, 0);
          }
        }
    }
    __syncthreads();
  }

  const float* b1e = b1 + (size_t)e * DH;
  const float* b2e = b2 + (size_t)e * DH;
#pragma unroll
  for (int mi = 0; mi < 4; mi++)
#pragma unroll
    for (int ni = 0; ni < 4; ni++)
#pragma unroll
      for (int r = 0; r < 4; r++) {
        int row = mbase + wr * 64 + mi * 16 + (lane >> 4) * 4 + r;
        int col = nbase + wc * 64 + ni * 16 + (lane & 15);
        float u = uacc[mi][ni][r] + b1e[col];
        float v = vacc[mi][ni][r] + b2e[col];
        float hv = u / (1.f + expf(-u)) * v;   // silu(u) * v
        _Float16 hi = (_Float16)hv;
        hhi[(size_t)row * DH + col] = hi;
        if (SPLIT) hlo[(size_t)row * DH + col] = (_Float16)(hv - (float)hi);
      }
}

// ---- GEMM2: y = h @ w3 + b3.  WRITE_Y: plain stores to ybuf (combine later).
//      else: out += prob * y via atomics (fallback when ws is small). ----
template <bool SPLIT, bool WRITE_Y>
__global__ __launch_bounds__(256) void gemm2_kernel(
    const _Float16* __restrict__ hhi, const _Float16* __restrict__ hlo,
    const _Float16* __restrict__ w3h, const _Float16* __restrict__ w3l,
    const float* __restrict__ b3, const int* __restrict__ rtok,
    const float* __restrict__ rprob, const int* __restrict__ segoff,
    float* __restrict__ ybuf, float* __restrict__ out) {
  // XCD swizzle: each XCD owns 1 N-panel across all M
  int dflat = blockIdx.y * 136 + blockIdx.x;     // grid (136,8) = 1088 = 8*136
  int xcd = dflat & 7, j = dflat >> 3;           // j in [0,136)
  int mbase = j * TILE_M;
  if (mbase >= segoff[8]) return;
  int e = 0;
  while (mbase >= segoff[e + 1]) e++;
  int nbase = xcd * 128;

  extern __shared__ char smem[];               // SPLIT: 32 KB, else 16 KB
  _Float16* Ah = (_Float16*)smem;              // [128*32] each
  _Float16* Bh = Ah + 4096;
  _Float16* Al = Bh + 4096;
  _Float16* Bl = Al + 4096;

  int t = threadIdx.x;
  int lane = t & 63, wave = t >> 6;
  int wr = wave >> 1, wc = wave & 1;

  int r0 = t >> 2, part = t & 3;
  int r1 = 64 + r0;
  size_t offA0 = (size_t)(mbase + r0) * DH + part * 8;
  size_t offA1 = (size_t)(mbase + r1) * DH + part * 8;
  size_t offB0 = ((size_t)e * DM + nbase + r0) * DH + part * 8;
  size_t offB1 = ((size_t)e * DM + nbase + r1) * DH + part * 8;
  int l0 = wave * 1024, l1 = 4096 + wave * 1024;

  f32x4 acc[4][4];
#pragma unroll
  for (int a = 0; a < 4; a++)
#pragma unroll
    for (int b = 0; b < 4; b++) acc[a][b] = {0.f,0.f,0.f,0.f};

  for (int kk = 0; kk < DH; kk += 32) {
    gload16(hhi + offA0 + kk, (char*)Ah + l0);
    gload16(hhi + offA1 + kk, (char*)Ah + l1);
    gload16(w3h + offB0 + kk, (char*)Bh + l0);
    gload16(w3h + offB1 + kk, (char*)Bh + l1);
    if (SPLIT) {
      gload16(hlo + offA0 + kk, (char*)Al + l0);
      gload16(hlo + offA1 + kk, (char*)Al + l1);
      gload16(w3l + offB0 + kk, (char*)Bl + l0);
      gload16(w3l + offB1 + kk, (char*)Bl + l1);
    }
    __syncthreads();
    int kpos = (lane >> 4) * 8;
    half8 ah[4], al[4], bh[4], bl[4];
#pragma unroll
    for (int i = 0; i < 4; i++) {
      int rowA = wr * 64 + i * 16 + (lane & 15);
      int rowB = wc * 64 + i * 16 + (lane & 15);
      ah[i] = *(const half8*)&Ah[rowA * 32 + kpos];
      bh[i] = *(const half8*)&Bh[rowB * 32 + kpos];
      if (SPLIT) {
        al[i] = *(const half8*)&Al[rowA * 32 + kpos];
        bl[i] = *(const half8*)&Bl[rowB * 32 + kpos];
      }
    }
#pragma unroll
    for (int mi = 0; mi < 4; mi++)
#pragma unroll
      for (int ni = 0; ni < 4; ni++) {
        acc[mi][ni] = __builtin_amdgcn_mfma_f32_16x16x32_f16(ah[mi], bh[ni], acc[mi][ni], 0, 0, 0);
        if (SPLIT) {
          acc[mi][ni] = __builtin_amdgcn_mfma_f32_16x16x32_f16(ah[mi], bl[ni], acc[mi][ni], 0, 0, 0);
          acc[mi][ni] = __builtin_amdgcn_mfma_f32_16x16x32_f16(al[mi], bh[ni], acc[mi][ni], 0, 0, 0);
        }
      }
    __syncthreads();
  }

  const float* b3e = b3 + (size_t)e * DM;
#pragma unroll
  for (int mi = 0; mi < 4; mi++)
#pragma unroll
    for (int r = 0; r < 4; r++) {
      int row = mbase + wr * 64 + mi * 16 + (lane >> 4) * 4 + r;
      if (WRITE_Y) {
#pragma unroll
        for (int ni = 0; ni < 4; ni++) {
          int col = nbase + wc * 64 + ni * 16 + (lane & 15);
          ybuf[(size_t)row * DM + col] = acc[mi][ni][r] + b3e[col];
        }
      } else {
        int tok = rtok[row];
        if (tok < 0) continue;                      // padded row
        float pr = rprob[row];
#pragma unroll
        for (int ni = 0; ni < 4; ni++) {
          int col = nbase + wc * 64 + ni * 16 + (lane & 15);
          float val = (acc[mi][ni][r] + b3e[col]) * pr;
          atomicAdd(&out[(size_t)tok * DM + col], val);
        }
      }
    }
}

// ---- combine: out[tok] = p0 * y[row0] + p1 * y[row1] (float4, coalesced) ----
__global__ __launch_bounds__(256) void combine_kernel(
    const float4* __restrict__ ybuf, const int* __restrict__ inv,
    const float* __restrict__ tok_p, float4* __restrict__ out) {
  int gid = blockIdx.x * 256 + threadIdx.x;       // NTOK*DM/4 threads
  int tok = gid >> 8;                              // DM/4 = 256 float4 per token
  int c4  = gid & 255;
  int r0 = inv[tok * 2], r1 = inv[tok * 2 + 1];
  float p0 = tok_p[tok * 2], p1 = tok_p[tok * 2 + 1];
  float4 a = ybuf[(size_t)r0 * 256 + c4];
  float4 b = ybuf[(size_t)r1 * 256 + c4];
  float4 o;
  o.x = p0 * a.x + p1 * b.x;
  o.y = p0 * a.y + p1 * b.y;
  o.z = p0 * a.z + p1 * b.z;
  o.w = p0 * a.w + p1 * b.w;
  out[gid] = o;
}

// ---------------------------------------------------------------------------
extern "C" void kernel_launch(void* const* d_in, const int* in_sizes, int n_in,
                              void* d_out, int out_size, void* d_ws, size_t ws_size,
                              hipStream_t stream) {
  const float* x      = (const float*)d_in[0];
  const float* gate_w = (const float*)d_in[1];
  const float* gate_b = (const float*)d_in[2];
  const float* w1     = (const float*)d_in[3];
  const float* b1     = (const float*)d_in[4];
  const float* w2     = (const float*)d_in[5];
  const float* b2     = (const float*)d_in[6];
  const float* w3     = (const float*)d_in[7];
  const float* b3     = (const float*)d_in[8];
  float* out = (float*)d_out;

  const size_t SZ_XH = (size_t)NTOK * DM * 2;        // 16.78 MB
  const size_t SZ_W  = (size_t)NEXP * DM * DH * 2;   // 33.55 MB
  const size_t SZ_H  = (size_t)WC_ROWS * DH * 2;     // 71.30 MB
  const size_t SZ_Y  = (size_t)WC_ROWS * DM * 4;     // 71.30 MB
  const size_t SZ_RT = (size_t)WC_ROWS * 4;
  const size_t SZ_NP = (size_t)NPAIR * 4;

  char* ws = (char*)d_ws;
  // ctrl (256 B): imp[8] f32 @0, cnt[8] i32 @32, cursor[8] i32 @64, segoff[9] i32 @96
  float* g_imp  = (float*)(ws + 0);
  int*   g_cnt  = (int*)(ws + 32);
  int*   cursor = (int*)(ws + 64);
  int*   segoff = (int*)(ws + 96);

  // Tier A (split) layout
  size_t o = 256;
  _Float16 *A_xhi, *A_xlo, *A_w1h, *A_w1l, *A_w2h, *A_w2l, *A_w3h, *A_w3l, *A_hhi, *A_hlo;
  int *A_rtok, *A_toke, *A_inv; float *A_rprob, *A_tokp, *A_y;
  A_xhi = (_Float16*)(ws + o); o += SZ_XH;
  A_xlo = (_Float16*)(ws + o); o += SZ_XH;
  A_w1h = (_Float16*)(ws + o); o += SZ_W;
  A_w1l = (_Float16*)(ws + o); o += SZ_W;
  A_w2h = (_Float16*)(ws + o); o += SZ_W;
  A_w2l = (_Float16*)(ws + o); o += SZ_W;
  A_w3h = (_Float16*)(ws + o); o += SZ_W;
  A_w3l = (_Float16*)(ws + o); o += SZ_W;
  A_hhi = (_Float16*)(ws + o); o += SZ_H;
  A_hlo = (_Float16*)(ws + o); o += SZ_H;
  A_rtok = (int*)(ws + o);   o += SZ_RT;
  A_rprob= (float*)(ws + o); o += SZ_RT;
  A_toke = (int*)(ws + o);   o += SZ_NP;
  A_tokp = (float*)(ws + o); o += SZ_NP;
  A_inv  = (int*)(ws + o);   o += SZ_NP;
  A_y    = (float*)(ws + o); o += SZ_Y;
  size_t offA = o;                                   // ~449.1 MB

  // Tier B/C (single fp16) layout
  o = 256;
  _Float16 *B_xh, *B_w1, *B_w2, *B_w3, *B_h;
  int *B_rtok, *B_toke, *B_inv; float *B_rprob, *B_tokp, *B_y;
  B_xh = (_Float16*)(ws + o); o += SZ_XH;
  B_w1 = (_Float16*)(ws + o); o += SZ_W;
  B_w2 = (_Float16*)(ws + o); o += SZ_W;
  B_w3 = (_Float16*)(ws + o); o += SZ_W;
  B_h  = (_Float16*)(ws + o); o += SZ_H;
  B_rtok = (int*)(ws + o);   o += SZ_RT;
  B_rprob= (float*)(ws + o); o += SZ_RT;
  B_toke = (int*)(ws + o);   o += SZ_NP;
  B_tokp = (float*)(ws + o); o += SZ_NP;
  B_inv  = (int*)(ws + o);   o += SZ_NP;
  size_t offC = o;                                   // ~189.1 MB
  B_y    = (float*)(ws + o); o += SZ_Y;
  size_t offB = o;                                   // ~260.4 MB

  int mode = (ws_size >= offA) ? 2 : (ws_size >= offB) ? 1 : 0;  // constant -> graph-safe
  (void)offC;

  if (mode == 2) {
    init_kernel<<<2048, 256, 0, stream>>>((float4*)out, NTOK * DM / 4,
                                          out + (size_t)NTOK * DM, A_rtok, A_rprob, (int*)ws);
    transpose_cvt_kernel<true><<<dim3(512, 8, 3), dim3(32, 8), 0, stream>>>(
        w1, w2, w3, A_w1h, A_w1l, A_w2h, A_w2l, A_w3h, A_w3l);
    router_kernel<true><<<NTOK / 4, 256, 0, stream>>>(x, gate_w, gate_b, g_imp, g_cnt,
                                                      A_toke, A_tokp, A_xhi, A_xlo);
    offsets_aux_kernel<<<1, 64, 0, stream>>>(g_imp, g_cnt, segoff, out + (size_t)NTOK * DM);
    scatter_rows_kernel<<<NPAIR / 256, 256, 0, stream>>>(A_toke, A_tokp, segoff, cursor,
                                                         A_rtok, A_rprob, A_inv);
    gemm1_kernel<true><<<dim3(136, 16), 256, 49152, stream>>>(
        A_xhi, A_xlo, A_w1h, A_w1l, A_w2h, A_w2l, b1, b2, A_rtok, segoff, A_hhi, A_hlo);
    gemm2_kernel<true, true><<<dim3(136, 8), 256, 32768, stream>>>(
        A_hhi, A_hlo, A_w3h, A_w3l, b3, A_rtok, A_rprob, segoff, A_y, out);
    combine_kernel<<<NTOK * DM / 4 / 256, 256, 0, stream>>>((const float4*)A_y, A_inv,
                                                            A_tokp, (float4*)out);
  } else {
    init_kernel<<<2048, 256, 0, stream>>>((float4*)out, NTOK * DM / 4,
                                          out + (size_t)NTOK * DM, B_rtok, B_rprob, (int*)ws);
    transpose_cvt_kernel<false><<<dim3(512, 8, 3), dim3(32, 8), 0, stream>>>(
        w1, w2, w3, B_w1, nullptr, B_w2, nullptr, B_w3, nullptr);
    router_kernel<false><<<NTOK / 4, 256, 0, stream>>>(x, gate_w, gate_b, g_imp, g_cnt,
                                                       B_toke, B_tokp, B_xh, nullptr);
    offsets_aux_kernel<<<1, 64, 0, stream>>>(g_imp, g_cnt, segoff, out + (size_t)NTOK * DM);
    scatter_rows_kernel<<<NPAIR / 256, 256, 0, stream>>>(B_toke, B_tokp, segoff, cursor,
                                                         B_rtok, B_rprob, B_inv);
    gemm1_kernel<false><<<dim3(136, 16), 256, 24576, stream>>>(
        B_xh, nullptr, B_w1, nullptr, B_w2, nullptr, b1, b2, B_rtok, segoff, B_h, nullptr);
    if (mode == 1) {
      gemm2_kernel<false, true><<<dim3(136, 8), 256, 16384, stream>>>(
          B_h, nullptr, B_w3, nullptr, b3, B_rtok, B_rprob, segoff, B_y, out);
      combine_kernel<<<NTOK * DM / 4 / 256, 256, 0, stream>>>((const float4*)B_y, B_inv,
                                                              B_tokp, (float4*)out);
    } else {
      gemm2_kernel<false, false><<<dim3(136, 8), 256, 16384, stream>>>(
          B_h, nullptr, B_w3, nullptr, b3, B_rtok, B_rprob, segoff, B_y, out);
    }
  }
}

// Round 6
// 699.195 us; speedup vs baseline: 1.1760x; 1.1760x over previous
//
#include <hip/hip_runtime.h>
#include <stdint.h>

// ---------------------------------------------------------------------------
// MoE forward, routed top-2. fp16 single-pass MFMA GEMMs (validated: absmax
// 0.0156 PASS on hardware, round 4).
// This round (re-submit of unmeasured round-5 + __expf): LDS XOR-swizzle
// (kills 8-way bank conflict on ds_read_b128; SQ_LDS_BANK_CONFLICT was
// 1.3e7) + double-buffered LDS with 1 barrier/K-step (T3 minimum-2-phase
// recipe: stage overlaps MFMA) + setprio around MFMA cluster.
// ---------------------------------------------------------------------------

#define NTOK     8192          // B*T
#define DM       1024          // D_MODEL
#define DH       2048          // D_HIDDEN
#define NEXP     8
#define NPAIR    16384         // NTOK * TOP_K
#define TILE_M   128
#define GRID_M   136           // ceil((16384 + 8*127)/128) = 136 (divisible by 8)
#define WC_ROWS  (GRID_M * TILE_M)   // 17408

typedef _Float16 half8 __attribute__((ext_vector_type(8)));
typedef float    f32x4 __attribute__((ext_vector_type(4)));
typedef unsigned int u32;

__device__ __forceinline__ void gload16(const void* g, void* l) {
  __builtin_amdgcn_global_load_lds(
      (const __attribute__((address_space(1))) u32*)g,
      (__attribute__((address_space(3))) u32*)l, 16, 0, 0);
}

// ---------------- init: zero out, rtok=-1, rprob=0, ctrl=0 ----------------
__global__ void init_kernel(float4* __restrict__ out4, int n4, float* __restrict__ aux,
                            int* __restrict__ rtok, float* __restrict__ rprob,
                            int* __restrict__ ctrl) {
  int gid = blockIdx.x * 256 + threadIdx.x;
  int stride = gridDim.x * 256;
  float4 z4 = {0.f, 0.f, 0.f, 0.f};
  for (int i = gid; i < n4; i += stride) out4[i] = z4;
  for (int i = gid; i < WC_ROWS; i += stride) { rtok[i] = -1; rprob[i] = 0.f; }
  if (gid < 64) ctrl[gid] = 0;
  if (gid == 0) *aux = 0.f;
}

// ---- transpose+cvt weights: [E][R][C] f32 -> [E][C][R] f16 ----------------
__global__ __launch_bounds__(256) void transpose_cvt_kernel(
    const float* __restrict__ w1, const float* __restrict__ w2, const float* __restrict__ w3,
    _Float16* __restrict__ w1t, _Float16* __restrict__ w2t, _Float16* __restrict__ w3t) {
  int z = blockIdx.z;
  int R = (z == 2) ? DH : DM;
  int C = (z == 2) ? DM : DH;
  const float* in = (z == 0) ? w1 : (z == 1) ? w2 : w3;
  _Float16*   out = (z == 0) ? w1t : (z == 1) ? w2t : w3t;
  size_t ebase = (size_t)blockIdx.y * R * C;
  in += ebase;
  int tilesC = C >> 5;
  int tr = blockIdx.x / tilesC, tc = blockIdx.x % tilesC;
  int r0 = tr << 7, c0 = tc << 5;
  __shared__ float tsh[32][129];
  int tx = threadIdx.x, ty = threadIdx.y;   // (32, 8)
#pragma unroll
  for (int i = 0; i < 16; i++) {
    int r = ty + i * 8;
    tsh[tx][r] = in[(size_t)(r0 + r) * C + c0 + tx];
  }
  __syncthreads();
  int tid = ty * 32 + tx;
  int c = tid >> 3, g = tid & 7;            // 32 out-rows x 8 chunks of 16
  const float* trow = &tsh[c][g * 16];
  _Float16 tmp[16];
#pragma unroll
  for (int j = 0; j < 16; j++) tmp[j] = (_Float16)trow[j];
  half8* dst = (half8*)(out + ebase + (size_t)(c0 + c) * R + r0 + g * 16);
  dst[0] = *(half8*)&tmp[0];
  dst[1] = *(half8*)&tmp[8];
}

// ---- router: logits, top-2 (stable), softmax, importance, counts, x->f16 ----
__global__ __launch_bounds__(256) void router_kernel(
    const float* __restrict__ x, const float* __restrict__ gw, const float* __restrict__ gb,
    float* __restrict__ g_imp, int* __restrict__ g_cnt,
    int* __restrict__ tok_e, float* __restrict__ tok_p, _Float16* __restrict__ xh) {
  __shared__ float s_imp[8];
  __shared__ int   s_cnt[8];
  int t = threadIdx.x;
  if (t < 8) { s_imp[t] = 0.f; s_cnt[t] = 0; }
  __syncthreads();
  int wave = t >> 6, lane = t & 63;
  int tok = blockIdx.x * 4 + wave;
  const float4* xr = (const float4*)(x + (size_t)tok * DM);
  float acc[8] = {0.f,0.f,0.f,0.f,0.f,0.f,0.f,0.f};
  _Float16 hh[16];
#pragma unroll
  for (int j = 0; j < 4; j++) {
    float4 v = xr[lane * 4 + j];
    const float* gw0 = gw + (size_t)(lane * 16 + j * 4) * 8;
#pragma unroll
    for (int e = 0; e < 8; e++)
      acc[e] += v.x * gw0[e] + v.y * gw0[8 + e] + v.z * gw0[16 + e] + v.w * gw0[24 + e];
    hh[j * 4 + 0] = (_Float16)v.x; hh[j * 4 + 1] = (_Float16)v.y;
    hh[j * 4 + 2] = (_Float16)v.z; hh[j * 4 + 3] = (_Float16)v.w;
  }
  half8* xo = (half8*)(xh + (size_t)tok * DM + lane * 16);
  xo[0] = *(half8*)&hh[0];
  xo[1] = *(half8*)&hh[8];
#pragma unroll
  for (int off = 32; off > 0; off >>= 1) {
#pragma unroll
    for (int e = 0; e < 8; e++) acc[e] += __shfl_xor(acc[e], off, 64);
  }
  if (lane == 0) {
    float l[8];
#pragma unroll
    for (int e = 0; e < 8; e++) l[e] = acc[e] + gb[e];
    float v0 = l[0]; int i0 = 0;
#pragma unroll
    for (int e = 1; e < 8; e++) if (l[e] > v0) { v0 = l[e]; i0 = e; }
    float v1 = -3.4e38f; int i1 = -1;
#pragma unroll
    for (int e = 0; e < 8; e++) {
      if (e != i0 && l[e] > v1) { v1 = l[e]; i1 = e; }
    }
    float s = 0.f, p[8];
#pragma unroll
    for (int e = 0; e < 8; e++) { p[e] = expf(l[e] - v0); s += p[e]; }
    float inv = 1.f / s;
#pragma unroll
    for (int e = 0; e < 8; e++) atomicAdd(&s_imp[e], p[e] * inv);
    float e1 = expf(v1 - v0);
    float p0 = 1.f / (1.f + e1);
    tok_e[tok * 2] = i0;  tok_e[tok * 2 + 1] = i1;
    tok_p[tok * 2] = p0;  tok_p[tok * 2 + 1] = e1 * p0;
    atomicAdd(&s_cnt[i0], 1); atomicAdd(&s_cnt[i1], 1);
  }
  __syncthreads();
  if (t < 8) { atomicAdd(&g_imp[t], s_imp[t]); atomicAdd(&g_cnt[t], s_cnt[t]); }
}

// ---------------- segment offsets (128-aligned) + aux loss ----------------
__global__ void offsets_aux_kernel(const float* __restrict__ g_imp, const int* __restrict__ g_cnt,
                                   int* __restrict__ segoff, float* __restrict__ aux_out) {
  if (threadIdx.x == 0 && blockIdx.x == 0) {
    int off = 0;
    segoff[0] = 0;
    double aux = 0.0;
    for (int e = 0; e < 8; e++) {
      off += ((g_cnt[e] + TILE_M - 1) >> 7) << 7;
      segoff[e + 1] = off;
      aux += (double)g_imp[e] * (double)g_cnt[e];
    }
    aux_out[0] = (float)(aux * 8.0 / ((double)NTOK * (double)NPAIR));
  }
}

// ---- scatter (token,prob) into expert segments, block-aggregated cursor ----
__global__ __launch_bounds__(256) void scatter_rows_kernel(
    const int* __restrict__ tok_e, const float* __restrict__ tok_p,
    const int* __restrict__ segoff, int* __restrict__ cursor,
    int* __restrict__ rtok, float* __restrict__ rprob, int* __restrict__ inv) {
  __shared__ int lcnt[8], lbase[8];
  int t = threadIdx.x;
  if (t < 8) lcnt[t] = 0;
  __syncthreads();
  int i = blockIdx.x * 256 + t;          // NPAIR = 64*256 exactly
  int e = tok_e[i];
  int lpos = atomicAdd(&lcnt[e], 1);
  __syncthreads();
  if (t < 8) lbase[t] = (lcnt[t] > 0) ? atomicAdd(&cursor[t], lcnt[t]) : 0;
  __syncthreads();
  int r = segoff[e] + lbase[e] + lpos;
  rtok[r]  = i >> 1;
  rprob[r] = tok_p[i];
  inv[i]   = r;
}

// ---- GEMM1: u=x@w1+b1, v=x@w2+b2, h=silu(u)*v (fp16 out) -------------------
// 128x128 tile (x2 outputs), BK=32, dbuf LDS + XOR-swizzle, 1 barrier/K-step.
__global__ __launch_bounds__(256) void gemm1_kernel(
    const _Float16* __restrict__ xh, const _Float16* __restrict__ w1t,
    const _Float16* __restrict__ w2t, const float* __restrict__ b1,
    const float* __restrict__ b2, const int* __restrict__ rtok,
    const int* __restrict__ segoff, _Float16* __restrict__ hbuf) {
  // XCD swizzle: each XCD owns 2 contiguous N-panels across all M
  int dflat = blockIdx.y * 136 + blockIdx.x;     // grid (136,16) = 2176 = 8*272
  int xcd = dflat & 7, j = dflat >> 3;           // j in [0,272)
  int wy = xcd * 2 + (j >= 136 ? 1 : 0);
  int wx = (j >= 136) ? j - 136 : j;
  int mbase = wx * TILE_M;
  if (mbase >= segoff[8]) return;
  int e = 0;
  while (mbase >= segoff[e + 1]) e++;
  int nbase = wy * 128;

  __shared__ _Float16 smem[2][3][4096];          // dbuf x {A,B1,B2} x 8KB

  int t = threadIdx.x;
  int lane = t & 63, wave = t >> 6;
  int wr = wave >> 1, wc = wave & 1;

  // staging: thread t -> LDS row r0=t>>2 (and r0+64), physical slot t&3.
  // Swizzle: phys slot s of row r holds global chunk s ^ ((r>>1)&3);
  // pre-swizzled GLOBAL source chunk, linear LDS dest (rule #21).
  int r0 = t >> 2;
  int r1 = 64 + r0;
  int partg = (t & 3) ^ ((t >> 3) & 3);          // (t>>3)&3 == (r0>>1)&3 == (r1>>1)&3
  int tokA0 = rtok[mbase + r0]; if (tokA0 < 0) tokA0 = 0;
  int tokA1 = rtok[mbase + r1]; if (tokA1 < 0) tokA1 = 0;
  size_t offA0 = (size_t)tokA0 * DM + partg * 8;
  size_t offA1 = (size_t)tokA1 * DM + partg * 8;
  size_t offB0 = ((size_t)e * DH + nbase + r0) * DM + partg * 8;
  size_t offB1 = ((size_t)e * DH + nbase + r1) * DM + partg * 8;
  int l0 = wave * 1024, l1 = 4096 + wave * 1024; // byte offsets within a tile

  f32x4 uacc[4][4], vacc[4][4];
#pragma unroll
  for (int a = 0; a < 4; a++)
#pragma unroll
    for (int b = 0; b < 4; b++) { uacc[a][b] = {0.f,0.f,0.f,0.f}; vacc[a][b] = {0.f,0.f,0.f,0.f}; }

  auto STAGE = [&](int buf, int kk) {
    char* base = (char*)&smem[buf][0][0];
    gload16(xh  + offA0 + kk, base + l0);
    gload16(xh  + offA1 + kk, base + l1);
    gload16(w1t + offB0 + kk, base + 8192 + l0);
    gload16(w1t + offB1 + kk, base + 8192 + l1);
    gload16(w2t + offB0 + kk, base + 16384 + l0);
    gload16(w2t + offB1 + kk, base + 16384 + l1);
  };

  // swizzled read slot offset (elements): lane-constant
  int kgrp = lane >> 4;
  int sOff = ((kgrp ^ ((lane >> 1) & 3)) << 3);  // (rowA>>1)&3 == (lane>>1)&3

  STAGE(0, 0);
  __syncthreads();                                // drain prologue loads
  int cur = 0;
  for (int kk = 0; kk < DM; kk += 32) {
    if (kk + 32 < DM) STAGE(cur ^ 1, kk + 32);   // loads in flight during compute
    const _Float16* Ac  = &smem[cur][0][0];
    const _Float16* B1c = &smem[cur][1][0];
    const _Float16* B2c = &smem[cur][2][0];
    half8 af[4];
#pragma unroll
    for (int i = 0; i < 4; i++) {
      int rowA = wr * 64 + i * 16 + (lane & 15);
      af[i] = *(const half8*)&Ac[rowA * 32 + sOff];
    }
    __builtin_amdgcn_s_setprio(1);
    {
      half8 bf[4];
#pragma unroll
      for (int i = 0; i < 4; i++) {
        int rowB = wc * 64 + i * 16 + (lane & 15);
        bf[i] = *(const half8*)&B1c[rowB * 32 + sOff];
      }
#pragma unroll
      for (int mi = 0; mi < 4; mi++)
#pragma unroll
        for (int ni = 0; ni < 4; ni++)
          uacc[mi][ni] = __builtin_amdgcn_mfma_f32_16x16x32_f16(af[mi], bf[ni], uacc[mi][ni], 0, 0, 0);
    }
    {
      half8 bf[4];
#pragma unroll
      for (int i = 0; i < 4; i++) {
        int rowB = wc * 64 + i * 16 + (lane & 15);
        bf[i] = *(const half8*)&B2c[rowB * 32 + sOff];
      }
#pragma unroll
      for (int mi = 0; mi < 4; mi++)
#pragma unroll
        for (int ni = 0; ni < 4; ni++)
          vacc[mi][ni] = __builtin_amdgcn_mfma_f32_16x16x32_f16(af[mi], bf[ni], vacc[mi][ni], 0, 0, 0);
    }
    __builtin_amdgcn_s_setprio(0);
    __syncthreads();                              // drains next-tile stage; protects buf reuse
    cur ^= 1;
  }

  const float* b1e = b1 + (size_t)e * DH;
  const float* b2e = b2 + (size_t)e * DH;
#pragma unroll
  for (int mi = 0; mi < 4; mi++)
#pragma unroll
    for (int ni = 0; ni < 4; ni++)
#pragma unroll
      for (int r = 0; r < 4; r++) {
        int row = mbase + wr * 64 + mi * 16 + (lane >> 4) * 4 + r;
        int col = nbase + wc * 64 + ni * 16 + (lane & 15);
        float u = uacc[mi][ni][r] + b1e[col];
        float v = vacc[mi][ni][r] + b2e[col];
        float hv = u / (1.f + __expf(-u)) * v;   // silu(u) * v
        hbuf[(size_t)row * DH + col] = (_Float16)hv;
      }
}

// ---- GEMM2: y = h @ w3 + b3.  WRITE_Y: plain stores to ybuf (combine later).
//      else: out += prob * y via atomics (fallback when ws is small). ----
template <bool WRITE_Y>
__global__ __launch_bounds__(256) void gemm2_kernel(
    const _Float16* __restrict__ hbuf, const _Float16* __restrict__ w3t,
    const float* __restrict__ b3, const int* __restrict__ rtok,
    const float* __restrict__ rprob, const int* __restrict__ segoff,
    float* __restrict__ ybuf, float* __restrict__ out) {
  // XCD swizzle: each XCD owns 1 N-panel across all M
  int dflat = blockIdx.y * 136 + blockIdx.x;     // grid (136,8) = 1088 = 8*136
  int xcd = dflat & 7, j = dflat >> 3;           // j in [0,136)
  int mbase = j * TILE_M;
  if (mbase >= segoff[8]) return;
  int e = 0;
  while (mbase >= segoff[e + 1]) e++;
  int nbase = xcd * 128;

  __shared__ _Float16 smem[2][2][4096];          // dbuf x {A,B} x 8KB

  int t = threadIdx.x;
  int lane = t & 63, wave = t >> 6;
  int wr = wave >> 1, wc = wave & 1;

  int r0 = t >> 2;
  int r1 = 64 + r0;
  int partg = (t & 3) ^ ((t >> 3) & 3);
  size_t offA0 = (size_t)(mbase + r0) * DH + partg * 8;
  size_t offA1 = (size_t)(mbase + r1) * DH + partg * 8;
  size_t offB0 = ((size_t)e * DM + nbase + r0) * DH + partg * 8;
  size_t offB1 = ((size_t)e * DM + nbase + r1) * DH + partg * 8;
  int l0 = wave * 1024, l1 = 4096 + wave * 1024;

  f32x4 acc[4][4];
#pragma unroll
  for (int a = 0; a < 4; a++)
#pragma unroll
    for (int b = 0; b < 4; b++) acc[a][b] = {0.f,0.f,0.f,0.f};

  auto STAGE = [&](int buf, int kk) {
    char* base = (char*)&smem[buf][0][0];
    gload16(hbuf + offA0 + kk, base + l0);
    gload16(hbuf + offA1 + kk, base + l1);
    gload16(w3t + offB0 + kk, base + 8192 + l0);
    gload16(w3t + offB1 + kk, base + 8192 + l1);
  };

  int kgrp = lane >> 4;
  int sOff = ((kgrp ^ ((lane >> 1) & 3)) << 3);

  STAGE(0, 0);
  __syncthreads();
  int cur = 0;
  for (int kk = 0; kk < DH; kk += 32) {
    if (kk + 32 < DH) STAGE(cur ^ 1, kk + 32);
    const _Float16* Ac = &smem[cur][0][0];
    const _Float16* Bc = &smem[cur][1][0];
    half8 af[4], bf[4];
#pragma unroll
    for (int i = 0; i < 4; i++) {
      int rowA = wr * 64 + i * 16 + (lane & 15);
      int rowB = wc * 64 + i * 16 + (lane & 15);
      af[i] = *(const half8*)&Ac[rowA * 32 + sOff];
      bf[i] = *(const half8*)&Bc[rowB * 32 + sOff];
    }
    __builtin_amdgcn_s_setprio(1);
#pragma unroll
    for (int mi = 0; mi < 4; mi++)
#pragma unroll
      for (int ni = 0; ni < 4; ni++)
        acc[mi][ni] = __builtin_amdgcn_mfma_f32_16x16x32_f16(af[mi], bf[ni], acc[mi][ni], 0, 0, 0);
    __builtin_amdgcn_s_setprio(0);
    __syncthreads();
    cur ^= 1;
  }

  const float* b3e = b3 + (size_t)e * DM;
#pragma unroll
  for (int mi = 0; mi < 4; mi++)
#pragma unroll
    for (int r = 0; r < 4; r++) {
      int row = mbase + wr * 64 + mi * 16 + (lane >> 4) * 4 + r;
      if (WRITE_Y) {
#pragma unroll
        for (int ni = 0; ni < 4; ni++) {
          int col = nbase + wc * 64 + ni * 16 + (lane & 15);
          ybuf[(size_t)row * DM + col] = acc[mi][ni][r] + b3e[col];
        }
      } else {
        int tok = rtok[row];
        if (tok < 0) continue;
        float pr = rprob[row];
#pragma unroll
        for (int ni = 0; ni < 4; ni++) {
          int col = nbase + wc * 64 + ni * 16 + (lane & 15);
          float val = (acc[mi][ni][r] + b3e[col]) * pr;
          atomicAdd(&out[(size_t)tok * DM + col], val);
        }
      }
    }
}

// ---- combine: out[tok] = p0 * y[row0] + p1 * y[row1] (float4, coalesced) ----
__global__ __launch_bounds__(256) void combine_kernel(
    const float4* __restrict__ ybuf, const int* __restrict__ inv,
    const float* __restrict__ tok_p, float4* __restrict__ out) {
  int gid = blockIdx.x * 256 + threadIdx.x;       // NTOK*DM/4 threads
  int tok = gid >> 8;                              // DM/4 = 256 float4 per token
  int c4  = gid & 255;
  int r0 = inv[tok * 2], r1 = inv[tok * 2 + 1];
  float p0 = tok_p[tok * 2], p1 = tok_p[tok * 2 + 1];
  float4 a = ybuf[(size_t)r0 * 256 + c4];
  float4 b = ybuf[(size_t)r1 * 256 + c4];
  float4 o;
  o.x = p0 * a.x + p1 * b.x;
  o.y = p0 * a.y + p1 * b.y;
  o.z = p0 * a.z + p1 * b.z;
  o.w = p0 * a.w + p1 * b.w;
  out[gid] = o;
}

// ---------------------------------------------------------------------------
extern "C" void kernel_launch(void* const* d_in, const int* in_sizes, int n_in,
                              void* d_out, int out_size, void* d_ws, size_t ws_size,
                              hipStream_t stream) {
  const float* x      = (const float*)d_in[0];
  const float* gate_w = (const float*)d_in[1];
  const float* gate_b = (const float*)d_in[2];
  const float* w1     = (const float*)d_in[3];
  const float* b1     = (const float*)d_in[4];
  const float* w2     = (const float*)d_in[5];
  const float* b2     = (const float*)d_in[6];
  const float* w3     = (const float*)d_in[7];
  const float* b3     = (const float*)d_in[8];
  float* out = (float*)d_out;

  const size_t SZ_XH = (size_t)NTOK * DM * 2;        // 16.78 MB
  const size_t SZ_W  = (size_t)NEXP * DM * DH * 2;   // 33.55 MB
  const size_t SZ_H  = (size_t)WC_ROWS * DH * 2;     // 71.30 MB
  const size_t SZ_Y  = (size_t)WC_ROWS * DM * 4;     // 71.30 MB
  const size_t SZ_RT = (size_t)WC_ROWS * 4;
  const size_t SZ_NP = (size_t)NPAIR * 4;

  char* ws = (char*)d_ws;
  // ctrl (256 B): imp[8] f32 @0, cnt[8] i32 @32, cursor[8] i32 @64, segoff[9] i32 @96
  float* g_imp  = (float*)(ws + 0);
  int*   g_cnt  = (int*)(ws + 32);
  int*   cursor = (int*)(ws + 64);
  int*   segoff = (int*)(ws + 96);

  size_t o = 256;
  _Float16* xh  = (_Float16*)(ws + o); o += SZ_XH;
  _Float16* w1t = (_Float16*)(ws + o); o += SZ_W;
  _Float16* w2t = (_Float16*)(ws + o); o += SZ_W;
  _Float16* w3t = (_Float16*)(ws + o); o += SZ_W;
  _Float16* hb  = (_Float16*)(ws + o); o += SZ_H;
  int*   rtok  = (int*)(ws + o);   o += SZ_RT;
  float* rprob = (float*)(ws + o); o += SZ_RT;
  int*   tok_e = (int*)(ws + o);   o += SZ_NP;
  float* tok_p = (float*)(ws + o); o += SZ_NP;
  int*   inv   = (int*)(ws + o);   o += SZ_NP;
  size_t offC = o;                                   // ~189.1 MB (atomic path)
  float* ybuf  = (float*)(ws + o); o += SZ_Y;
  size_t offB = o;                                   // ~260.4 MB (combine path)
  bool use_y = (ws_size >= offB);                    // constant -> graph-safe
  (void)offC;

  init_kernel<<<2048, 256, 0, stream>>>((float4*)out, NTOK * DM / 4,
                                        out + (size_t)NTOK * DM, rtok, rprob, (int*)ws);
  transpose_cvt_kernel<<<dim3(512, 8, 3), dim3(32, 8), 0, stream>>>(w1, w2, w3, w1t, w2t, w3t);
  router_kernel<<<NTOK / 4, 256, 0, stream>>>(x, gate_w, gate_b, g_imp, g_cnt, tok_e, tok_p, xh);
  offsets_aux_kernel<<<1, 64, 0, stream>>>(g_imp, g_cnt, segoff, out + (size_t)NTOK * DM);
  scatter_rows_kernel<<<NPAIR / 256, 256, 0, stream>>>(tok_e, tok_p, segoff, cursor,
                                                       rtok, rprob, inv);
  gemm1_kernel<<<dim3(136, 16), 256, 0, stream>>>(xh, w1t, w2t, b1, b2, rtok, segoff, hb);
  if (use_y) {
    gemm2_kernel<true><<<dim3(136, 8), 256, 0, stream>>>(hb, w3t, b3, rtok, rprob, segoff,
                                                         ybuf, out);
    combine_kernel<<<NTOK * DM / 4 / 256, 256, 0, stream>>>((const float4*)ybuf, inv, tok_p,
                                                            (float4*)out);
  } else {
    gemm2_kernel<false><<<dim3(136, 8), 256, 0, stream>>>(hb, w3t, b3, rtok, rprob, segoff,
                                                          ybuf, out);
  }
}